// Round 6
// baseline (412.544 us; speedup 1.0000x reference)
//
#include <hip/hip_runtime.h>

// out[b,n] = sum_{c,hw} x[b,c,hw] * W_s[n,hw] * W_d[n,c] + W_b[n]
// B=512, C=384, N=512, HW=169 (13x13).
//
// R6: prep_xf eliminated. Main kernel loads A-fragments DIRECTLY from the
// original fp32 x (two dword-aligned float4 loads per lane per frag) and
// converts to bf16 in-register via v_perm truncation (1 instr / pair).
// B-fragments (wsf, bf16, RNE) and WdT stay precomputed (tiny, L2-hot).
// K-loop remains barrier-free pure {load -> MFMA}; epilogue folds acc*WdT,
// shfl + 1KB LDS cross-wave reduce, atomicAdd per (block,n); bias on c_blk 0.

#define B_   512
#define C_   384
#define N_   512
#define HW_  169
#define CT   128
#define NT   128

#define WSF_ELEMS  ((size_t)32 * 6 * 64 * 8)       // 98,304
#define WDT_ELEMS  ((size_t)C_ * N_)               // 196,608

typedef __bf16 bf16x8 __attribute__((ext_vector_type(8)));
typedef float f32x4  __attribute__((ext_vector_type(4)));
typedef float f32x4a __attribute__((ext_vector_type(4), aligned(4)));  // dword-aligned ok

__device__ __forceinline__ __bf16 f2bf(float f) {
  union { float f; unsigned u; } v; v.f = f;
  unsigned r = (v.u + 0x7FFFu + ((v.u >> 16) & 1u)) >> 16;   // RNE
  unsigned short s = (unsigned short)r;
  return __builtin_bit_cast(__bf16, s);
}

// pack hi16(a), hi16(b) -> one dword (a in low half): bf16 truncation
__device__ __forceinline__ unsigned pack_trunc(float a, float b) {
  return __builtin_amdgcn_perm(__builtin_bit_cast(unsigned, b),
                               __builtin_bit_cast(unsigned, a), 0x07060302u);
}

// ---------------- prepass: wsf (B-fragment order) + WdT transpose ----------------

__global__ __launch_bounds__(256)
void prep_aux_kernel(const float* __restrict__ Ws,
                     const float* __restrict__ Wd,
                     __bf16* __restrict__ wsf,
                     float* __restrict__ WdT) {
  int t = blockIdx.x * 256 + threadIdx.x;
  if (t < 12288) {
    int lane = t & 63;
    int fr   = t >> 6;         // nm*6 + kb
    int kb   = fr % 6;
    int nm   = fr / 6;
    int m    = lane & 15;
    int q    = lane >> 4;
    int n    = nm * 16 + m;
    int k0   = kb * 32 + q * 8;
    const float* src = Ws + (size_t)n * HW_;
    bf16x8 v;
    #pragma unroll
    for (int j = 0; j < 8; ++j) {
      int k = k0 + j;
      float f = (k < HW_) ? src[k] : 0.f;
      v[j] = f2bf(f);
    }
    *(bf16x8*)(wsf + (size_t)t * 8) = v;
  } else {
    int i = t - 12288;         // [c][n]
    if (i < C_ * N_) {
      int c = i >> 9;
      int n = i & (N_ - 1);
      WdT[i] = Wd[n * C_ + c];
    }
  }
}

// ---------------- fast main kernel (barrier-free, fused x conversion) ----------------

__global__ __launch_bounds__(256)
void conv_main_fast(const float* __restrict__ x,
                    const __bf16* __restrict__ wsf,
                    const float* __restrict__ WdT,   // [c][n]
                    const float* __restrict__ Wb,
                    float* __restrict__ out) {
  __shared__ float red[4][64];     // 1 KB cross-wave reduce only

  const int tid  = threadIdx.x;
  // XCD swizzle: all 12 (n_blk,c_blk) blocks of one b share slot = b%8.
  const int id   = blockIdx.x;     // 0..6143
  const int slot = id & 7;
  const int grp  = id >> 3;        // 0..767
  const int sub  = grp % 12;       // n_blk*3 + c_blk
  const int b    = (grp / 12) * 8 + slot;
  const int n_blk = sub / 3;
  const int c_blk = sub % 3;
  const int n0    = n_blk * NT;

  const int lane  = tid & 63;
  const int wv    = tid >> 6;          // 4 waves: 2x2 (c,n) 64x64 quadrants
  const int cq    = (wv >> 1) * 64;
  const int nq    = (wv & 1) * 64;
  const int lrow  = lane & 15;
  const int lquad = lane >> 4;

  const int nm0 = (n0 + nq) >> 4;            // global 16-n fragment row
  const __bf16* bbase = wsf + ((size_t)nm0 * 6) * 512 + (size_t)lane * 8;

  // A rows in original x layout: row c = c_blk*128 + cq + mi*16 + lrow
  const float* arow[4];
  #pragma unroll
  for (int mi = 0; mi < 4; ++mi)
    arow[mi] = x + ((size_t)b * C_ + (c_blk * CT + cq + mi * 16 + lrow)) * HW_;

  const f32x4 zero = {0.f, 0.f, 0.f, 0.f};
  f32x4 acc[4][4];
  #pragma unroll
  for (int mi = 0; mi < 4; ++mi)
    #pragma unroll
    for (int ni = 0; ni < 4; ++ni)
      acc[mi][ni] = zero;

  #pragma unroll
  for (int kb = 0; kb < 6; ++kb) {
    bf16x8 afr[4], bfr[4];
    #pragma unroll
    for (int mi = 0; mi < 4; ++mi) {
      const float* ap = arow[mi] + kb * 32 + lquad * 8;   // k = kb*32+lquad*8
      uint4 d;
      if (kb < 5) {                       // k+7 <= 167 < 169: always in-range
        f32x4a lo = *(const f32x4a*)ap;
        f32x4a hi = *(const f32x4a*)(ap + 4);
        d.x = pack_trunc(lo[0], lo[1]);
        d.y = pack_trunc(lo[2], lo[3]);
        d.z = pack_trunc(hi[0], hi[1]);
        d.w = pack_trunc(hi[2], hi[3]);
      } else {                            // tail: k = 160+lquad*8
        if (lquad == 0) {                 // 160..167 all valid
          f32x4a lo = *(const f32x4a*)ap;
          f32x4a hi = *(const f32x4a*)(ap + 4);
          d.x = pack_trunc(lo[0], lo[1]);
          d.y = pack_trunc(lo[2], lo[3]);
          d.z = pack_trunc(hi[0], hi[1]);
          d.w = pack_trunc(hi[2], hi[3]);
        } else if (lquad == 1) {          // only k=168 valid
          d.x = pack_trunc(ap[0], 0.f);
          d.y = 0; d.z = 0; d.w = 0;
        } else {
          d.x = 0; d.y = 0; d.z = 0; d.w = 0;
        }
      }
      afr[mi] = __builtin_bit_cast(bf16x8, d);
    }
    // B fragments: direct global->VGPR, coalesced dwordx4, L2-hot
    #pragma unroll
    for (int ni = 0; ni < 4; ++ni)
      bfr[ni] = *(const bf16x8*)(bbase + ((size_t)ni * 6 + kb) * 512);
    #pragma unroll
    for (int mi = 0; mi < 4; ++mi)
      #pragma unroll
      for (int ni = 0; ni < 4; ++ni)
        acc[mi][ni] = __builtin_amdgcn_mfma_f32_16x16x32_bf16(
            afr[mi], bfr[ni], acc[mi][ni], 0, 0, 0);
  }

  // Fold: s[ni] = sum_c P[c,n] * WdT[c,n] for this block's 128-c slice.
  // C-layout: col(n) = lane&15, row(c) = (lane>>4)*4 + reg   [verified R1-R5]
  float s[4] = {0.f, 0.f, 0.f, 0.f};
  #pragma unroll
  for (int ni = 0; ni < 4; ++ni) {
    const int n = n0 + nq + ni * 16 + lrow;
    #pragma unroll
    for (int mi = 0; mi < 4; ++mi) {
      const int cbase = c_blk * CT + cq + mi * 16 + lquad * 4;
      #pragma unroll
      for (int i = 0; i < 4; ++i)
        s[ni] += acc[mi][ni][i] * WdT[(size_t)(cbase + i) * N_ + n];
    }
  }

  // intra-wave quad combine (disjoint c, same n)
  #pragma unroll
  for (int ni = 0; ni < 4; ++ni) {
    s[ni] += __shfl_xor(s[ni], 16, 64);
    s[ni] += __shfl_xor(s[ni], 32, 64);
  }
  if (lane < 16) {
    #pragma unroll
    for (int ni = 0; ni < 4; ++ni)
      red[wv][ni * 16 + lrow] = s[ni];
  }
  __syncthreads();

  // cross-wave: waves {0,2} share nq=0, {1,3} share nq=64 (disjoint c halves)
  if (tid < NT) {
    const int half = tid >> 6;
    const int idx  = tid & 63;
    const int n    = n0 + tid;
    float v = red[half][idx] + red[half + 2][idx];
    if (c_blk == 0) v += Wb[n];           // bias exactly once per (b,n)
    atomicAdd(&out[(size_t)b * N_ + n], v);
  }
}

// ---------------- fallback main kernel (no workspace needed) ----------------

#define LDSS 104
#define KCH  96

__global__ __launch_bounds__(256)
void conv_main_fallback(const float* __restrict__ x,
                        const float* __restrict__ Ws_g,
                        const float* __restrict__ Wd,
                        const float* __restrict__ Wb,
                        float* __restrict__ out) {
  __shared__ __align__(16) __bf16 Xs[CT][LDSS];
  __shared__ __align__(16) __bf16 Ws[NT][LDSS];

  const int tid   = threadIdx.x;
  const int n_blk = blockIdx.x;
  const int c_blk = blockIdx.y;
  const int b     = blockIdx.z;
  const int c0 = c_blk * CT;
  const int n0 = n_blk * NT;
  const int lane  = tid & 63;
  const int wv    = tid >> 6;
  const int cq    = (wv >> 1) * 64;
  const int nq    = (wv & 1) * 64;
  const int lrow  = lane & 15;
  const int lquad = lane >> 4;

  const f32x4 zero = {0.f, 0.f, 0.f, 0.f};
  f32x4 acc[4][4];
  #pragma unroll
  for (int mi = 0; mi < 4; ++mi)
    #pragma unroll
    for (int ni = 0; ni < 4; ++ni)
      acc[mi][ni] = zero;

  const float* xb  = x    + (size_t)b  * (C_ * HW_) + (size_t)c0 * HW_;
  const float* wsb = Ws_g + (size_t)n0 * HW_;

  for (int ch = 0; ch < 2; ++ch) {
    const int k0 = ch * KCH;
    __syncthreads();
    for (int e = tid; e < CT * KCH; e += 256) {
      int r   = e / KCH;
      int col = e - r * KCH;
      int k   = k0 + col;
      float vx = 0.f, vw = 0.f;
      if (k < HW_) {
        vx = xb [r * HW_ + k];
        vw = wsb[r * HW_ + k];
      }
      Xs[r][col] = f2bf(vx);
      Ws[r][col] = f2bf(vw);
    }
    __syncthreads();

    #pragma unroll
    for (int ks = 0; ks < 3; ++ks) {
      const int kc = ks * 32 + lquad * 8;
      bf16x8 afr[4], bfr[4];
      #pragma unroll
      for (int mi = 0; mi < 4; ++mi)
        afr[mi] = *(const bf16x8*)&Xs[cq + mi * 16 + lrow][kc];
      #pragma unroll
      for (int ni = 0; ni < 4; ++ni)
        bfr[ni] = *(const bf16x8*)&Ws[nq + ni * 16 + lrow][kc];
      #pragma unroll
      for (int mi = 0; mi < 4; ++mi)
        #pragma unroll
        for (int ni = 0; ni < 4; ++ni)
          acc[mi][ni] = __builtin_amdgcn_mfma_f32_16x16x32_bf16(
              afr[mi], bfr[ni], acc[mi][ni], 0, 0, 0);
    }
  }

  #pragma unroll
  for (int ni = 0; ni < 4; ++ni) {
    const int n = n0 + nq + ni * 16 + lrow;
    float sv = 0.f;
    #pragma unroll
    for (int mi = 0; mi < 4; ++mi) {
      const int cbase = c0 + cq + mi * 16 + lquad * 4;
      #pragma unroll
      for (int i = 0; i < 4; ++i)
        sv += acc[mi][ni][i] * Wd[(size_t)n * C_ + (cbase + i)];
    }
    sv += __shfl_xor(sv, 16, 64);
    sv += __shfl_xor(sv, 32, 64);
    if (lane < 16) {
      if (c_blk == 0 && cq == 0) sv += Wb[n];
      atomicAdd(&out[(size_t)b * N_ + n], sv);
    }
  }
}

extern "C" void kernel_launch(void* const* d_in, const int* in_sizes, int n_in,
                              void* d_out, int out_size, void* d_ws, size_t ws_size,
                              hipStream_t stream) {
  const float* x   = (const float*)d_in[0];   // [512,384,13,13]
  const float* Wsp = (const float*)d_in[1];   // [512,13,13]
  const float* Wd  = (const float*)d_in[2];   // [512,384]
  const float* Wb  = (const float*)d_in[3];   // [1,512]
  float* out = (float*)d_out;                 // [512,512] fp32

  hipMemsetAsync(d_out, 0, (size_t)out_size * sizeof(float), stream);

  const size_t need = WSF_ELEMS * sizeof(__bf16) + WDT_ELEMS * sizeof(float);

  if (ws_size >= need) {
    __bf16* wsf = (__bf16*)d_ws;
    float*  wdT = (float*)(wsf + WSF_ELEMS);

    prep_aux_kernel<<<(12288 + C_ * N_ + 255) / 256, 256, 0, stream>>>(Wsp, Wd, wsf, wdT);
    conv_main_fast<<<6144, 256, 0, stream>>>(x, wsf, wdT, Wb, out);
  } else {
    dim3 grid(N_ / NT, C_ / CT, B_);
    conv_main_fallback<<<grid, 256, 0, stream>>>(x, Wsp, Wd, Wb, out);
  }
}

// Round 7
// 286.312 us; speedup vs baseline: 1.4409x; 1.4409x over previous
//
#include <hip/hip_runtime.h>

// out[b,n] = sum_{c,hw} x[b,c,hw] * W_s[n,hw] * W_d[n,c] + W_b[n]
// B=512, C=384, N=512, HW=169 (13x13).
//
// R7 = R5 skeleton (barrier-free fragment-order main) + fast prep + wdf:
//   xf  bf16 [b][cm=24][kb=6][lane=64][8]   A-fragments (75.5 MB)
//   wsf bf16 [nm=32][kb=6][lane=64][8]      B-fragments (192 KB, L2-hot)
//   wdf f32  [cm=24][nm=32][lane=64][4]     W_d in MFMA C-layout order (786 KB)
// prep_xf v2: linear coalesced float4 slab load -> LDS -> RNE pack -> b128.
// main: pure {coalesced load -> MFMA} K-loop, no barriers; epilogue folds
// acc * wdf (coalesced dwordx4), shfl + 1KB LDS reduce, atomicAdd; bias c_blk0.
// R6 lesson: fragment-A from row-major x = 64-line gather per load -> never
// fuse the transpose into the consumer without LDS.

#define B_   512
#define C_   384
#define N_   512
#define HW_  169
#define CT   128
#define NT   128

#define XF_ELEMS   ((size_t)B_ * 24 * 6 * 64 * 8)  // 37,748,736 bf16 (75.5 MB)
#define WSF_ELEMS  ((size_t)32 * 6 * 64 * 8)       // 98,304 bf16
#define WDF_ELEMS  ((size_t)24 * 32 * 64 * 4)      // 196,608 f32 (786 KB)

typedef __bf16 bf16x8 __attribute__((ext_vector_type(8)));
typedef float f32x4  __attribute__((ext_vector_type(4)));
typedef float f32x4u __attribute__((ext_vector_type(4), aligned(4)));  // dword-aligned

__device__ __forceinline__ __bf16 f2bf(float f) {
  union { float f; unsigned u; } v; v.f = f;
  unsigned r = (v.u + 0x7FFFu + ((v.u >> 16) & 1u)) >> 16;   // RNE
  unsigned short s = (unsigned short)r;
  return __builtin_bit_cast(__bf16, s);
}

// ---------------- prep_xf v2: x -> A-fragment order ----------------
// Block = (b, g), g = 64-c-row group (C=384 = 6x64). Grid 3072, XCD-swizzled.
__global__ __launch_bounds__(256)
void prep_xf_kernel(const float* __restrict__ x, __bf16* __restrict__ xf) {
  __shared__ float Xl[64 * HW_];   // 43,264 B linear slab
  const int tid  = threadIdx.x;
  const int id   = blockIdx.x;
  const int slot = id & 7;
  const int q8   = id >> 3;        // 0..383
  const int g    = q8 % 6;
  const int b    = (q8 / 6) * 8 + slot;

  // coalesced linear slab copy: 2704 float4 (dword-aligned src)
  const float* src = x + ((size_t)b * C_ + g * 64) * HW_;
  for (int i = tid; i < 2704; i += 256)
    *(f32x4*)(Xl + i * 4) = *(const f32x4u*)(src + i * 4);
  __syncthreads();

  // 1536 fragment-slots; per p the slot's (cm_l, kb) are wave-uniform.
  #pragma unroll
  for (int p = 0; p < 6; ++p) {
    const int s    = p * 256 + tid;
    const int l    = s & 63;
    const int fr   = s >> 6;       // cm_l*6 + kb, wave-uniform
    const int kb   = fr % 6;
    const int cm_l = fr / 6;
    const int m    = l & 15;
    const int q    = l >> 4;
    const float* rp = Xl + (cm_l * 16 + m) * HW_;
    const int k0   = kb * 32 + q * 8;
    bf16x8 v;
    if (kb < 5 || q == 0) {                     // k0+7 <= 167 or tail-full quad
      #pragma unroll
      for (int j = 0; j < 8; ++j) v[j] = f2bf(rp[k0 + j]);
    } else if (q == 1) {                        // only k=168 valid
      v[0] = f2bf(rp[168]);
      #pragma unroll
      for (int j = 1; j < 8; ++j) v[j] = f2bf(0.f);
    } else {
      #pragma unroll
      for (int j = 0; j < 8; ++j) v[j] = f2bf(0.f);
    }
    *(bf16x8*)(xf + ((((size_t)b * 24 + g * 4 + cm_l) * 6 + kb) << 9) + (size_t)l * 8) = v;
  }
}

// ---------------- prep_aux: wsf (B-frag) + wdf (C-layout frag) ----------------
__global__ __launch_bounds__(256)
void prep_aux_kernel(const float* __restrict__ Ws,
                     const float* __restrict__ Wd,
                     __bf16* __restrict__ wsf,
                     float* __restrict__ wdf) {
  int t = blockIdx.x * 256 + threadIdx.x;      // 61440 total, exact
  if (t < 12288) {
    // wsf: t = (nm*6 + kb)*64 + lane
    int lane = t & 63;
    int fr   = t >> 6;
    int kb   = fr % 6;
    int nm   = fr / 6;
    int m    = lane & 15;
    int q    = lane >> 4;
    int n    = nm * 16 + m;
    int k0   = kb * 32 + q * 8;
    const float* src = Ws + (size_t)n * HW_;
    bf16x8 v;
    #pragma unroll
    for (int j = 0; j < 8; ++j) {
      int k = k0 + j;
      float f = (k < HW_) ? src[k] : 0.f;
      v[j] = f2bf(f);
    }
    *(bf16x8*)(wsf + (size_t)t * 8) = v;
  } else {
    // wdf: t2 = (cm*32 + nm)*64 + lane; elem i = Wd[n][cm*16 + q*4 + i]
    int t2 = t - 12288;                        // 0..49151
    int lane = t2 & 63;
    int fr   = t2 >> 6;                        // cm*32 + nm
    int nm   = fr & 31;
    int cm   = fr >> 5;
    int n    = nm * 16 + (lane & 15);
    int c0   = cm * 16 + (lane >> 4) * 4;
    f32x4 w = *(const f32x4u*)(Wd + (size_t)n * C_ + c0);   // 16B-aligned
    *(f32x4*)(wdf + (size_t)t2 * 4) = w;
  }
}

// ---------------- fast main kernel (barrier-free K-loop) ----------------
__global__ __launch_bounds__(256)
void conv_main_fast(const __bf16* __restrict__ xf,
                    const __bf16* __restrict__ wsf,
                    const float* __restrict__ wdf,
                    const float* __restrict__ Wb,
                    float* __restrict__ out) {
  __shared__ float red[4][64];     // 1 KB cross-wave reduce only

  const int tid  = threadIdx.x;
  // XCD swizzle: all 12 (n_blk,c_blk) blocks of one b share slot = b%8.
  const int id   = blockIdx.x;     // 0..6143
  const int slot = id & 7;
  const int grp  = id >> 3;        // 0..767
  const int sub  = grp % 12;       // n_blk*3 + c_blk
  const int b    = (grp / 12) * 8 + slot;
  const int n_blk = sub / 3;
  const int c_blk = sub % 3;
  const int n0    = n_blk * NT;

  const int lane  = tid & 63;
  const int wv    = tid >> 6;          // 4 waves: 2x2 (c,n) 64x64 quadrants
  const int cq    = (wv >> 1) * 64;
  const int nq    = (wv & 1) * 64;
  const int lrow  = lane & 15;

  const int nm0 = (n0 + nq) >> 4;            // global 16-n fragment row
  const int cm0 = c_blk * 8 + (cq >> 4);     // global 16-c fragment row

  const __bf16* abase = xf + (((size_t)b * 24 + cm0) * 6) * 512 + (size_t)lane * 8;
  const __bf16* bbase = wsf + ((size_t)nm0 * 6) * 512 + (size_t)lane * 8;

  const f32x4 zero = {0.f, 0.f, 0.f, 0.f};
  f32x4 acc[4][4];
  #pragma unroll
  for (int mi = 0; mi < 4; ++mi)
    #pragma unroll
    for (int ni = 0; ni < 4; ++ni)
      acc[mi][ni] = zero;

  // Pure load->MFMA stream; no barriers, no LDS staging.
  #pragma unroll
  for (int kb = 0; kb < 6; ++kb) {
    bf16x8 afr[4], bfr[4];
    #pragma unroll
    for (int mi = 0; mi < 4; ++mi)
      afr[mi] = *(const bf16x8*)(abase + ((size_t)mi * 6 + kb) * 512);
    #pragma unroll
    for (int ni = 0; ni < 4; ++ni)
      bfr[ni] = *(const bf16x8*)(bbase + ((size_t)ni * 6 + kb) * 512);
    #pragma unroll
    for (int mi = 0; mi < 4; ++mi)
      #pragma unroll
      for (int ni = 0; ni < 4; ++ni)
        acc[mi][ni] = __builtin_amdgcn_mfma_f32_16x16x32_bf16(
            afr[mi], bfr[ni], acc[mi][ni], 0, 0, 0);
  }

  // Fold: s[ni] = sum_c P[c,n] * W_d[n,c], wdf pre-permuted to C-layout.
  // C-layout: col(n) = lane&15, row(c) = (lane>>4)*4 + reg   [verified R1-R6]
  float s[4] = {0.f, 0.f, 0.f, 0.f};
  #pragma unroll
  for (int ni = 0; ni < 4; ++ni) {
    #pragma unroll
    for (int mi = 0; mi < 4; ++mi) {
      const f32x4 w = *(const f32x4*)(wdf +
          (((size_t)(cm0 + mi) * 32 + (nm0 + ni)) * 64 + lane) * 4);
      s[ni] += acc[mi][ni][0] * w[0] + acc[mi][ni][1] * w[1]
             + acc[mi][ni][2] * w[2] + acc[mi][ni][3] * w[3];
    }
  }

  // intra-wave quad combine (disjoint c, same n)
  #pragma unroll
  for (int ni = 0; ni < 4; ++ni) {
    s[ni] += __shfl_xor(s[ni], 16, 64);
    s[ni] += __shfl_xor(s[ni], 32, 64);
  }
  if (lane < 16) {
    #pragma unroll
    for (int ni = 0; ni < 4; ++ni)
      red[wv][ni * 16 + lrow] = s[ni];
  }
  __syncthreads();

  // cross-wave: waves {0,2} share nq=0, {1,3} share nq=64 (disjoint c halves)
  if (tid < NT) {
    const int half = tid >> 6;
    const int idx  = tid & 63;
    const int n    = n0 + tid;
    float v = red[half][idx] + red[half + 2][idx];
    if (c_blk == 0) v += Wb[n];           // bias exactly once per (b,n)
    atomicAdd(&out[(size_t)b * N_ + n], v);
  }
}

// ---------------- fallback main kernel (no workspace needed) ----------------

#define LDSS 104
#define KCH  96

__global__ __launch_bounds__(256)
void conv_main_fallback(const float* __restrict__ x,
                        const float* __restrict__ Ws_g,
                        const float* __restrict__ Wd,
                        const float* __restrict__ Wb,
                        float* __restrict__ out) {
  __shared__ __align__(16) __bf16 Xs[CT][LDSS];
  __shared__ __align__(16) __bf16 Ws[NT][LDSS];

  const int tid   = threadIdx.x;
  const int n_blk = blockIdx.x;
  const int c_blk = blockIdx.y;
  const int b     = blockIdx.z;
  const int c0 = c_blk * CT;
  const int n0 = n_blk * NT;
  const int lane  = tid & 63;
  const int wv    = tid >> 6;
  const int cq    = (wv >> 1) * 64;
  const int nq    = (wv & 1) * 64;
  const int lrow  = lane & 15;
  const int lquad = lane >> 4;

  const f32x4 zero = {0.f, 0.f, 0.f, 0.f};
  f32x4 acc[4][4];
  #pragma unroll
  for (int mi = 0; mi < 4; ++mi)
    #pragma unroll
    for (int ni = 0; ni < 4; ++ni)
      acc[mi][ni] = zero;

  const float* xb  = x    + (size_t)b  * (C_ * HW_) + (size_t)c0 * HW_;
  const float* wsb = Ws_g + (size_t)n0 * HW_;

  for (int ch = 0; ch < 2; ++ch) {
    const int k0 = ch * KCH;
    __syncthreads();
    for (int e = tid; e < CT * KCH; e += 256) {
      int r   = e / KCH;
      int col = e - r * KCH;
      int k   = k0 + col;
      float vx = 0.f, vw = 0.f;
      if (k < HW_) {
        vx = xb [r * HW_ + k];
        vw = wsb[r * HW_ + k];
      }
      Xs[r][col] = f2bf(vx);
      Ws[r][col] = f2bf(vw);
    }
    __syncthreads();

    #pragma unroll
    for (int ks = 0; ks < 3; ++ks) {
      const int kc = ks * 32 + lquad * 8;
      bf16x8 afr[4], bfr[4];
      #pragma unroll
      for (int mi = 0; mi < 4; ++mi)
        afr[mi] = *(const bf16x8*)&Xs[cq + mi * 16 + lrow][kc];
      #pragma unroll
      for (int ni = 0; ni < 4; ++ni)
        bfr[ni] = *(const bf16x8*)&Ws[nq + ni * 16 + lrow][kc];
      #pragma unroll
      for (int mi = 0; mi < 4; ++mi)
        #pragma unroll
        for (int ni = 0; ni < 4; ++ni)
          acc[mi][ni] = __builtin_amdgcn_mfma_f32_16x16x32_bf16(
              afr[mi], bfr[ni], acc[mi][ni], 0, 0, 0);
    }
  }

  #pragma unroll
  for (int ni = 0; ni < 4; ++ni) {
    const int n = n0 + nq + ni * 16 + lrow;
    float sv = 0.f;
    #pragma unroll
    for (int mi = 0; mi < 4; ++mi) {
      const int cbase = c0 + cq + mi * 16 + lquad * 4;
      #pragma unroll
      for (int i = 0; i < 4; ++i)
        sv += acc[mi][ni][i] * Wd[(size_t)n * C_ + (cbase + i)];
    }
    sv += __shfl_xor(sv, 16, 64);
    sv += __shfl_xor(sv, 32, 64);
    if (lane < 16) {
      if (c_blk == 0 && cq == 0) sv += Wb[n];
      atomicAdd(&out[(size_t)b * N_ + n], sv);
    }
  }
}

extern "C" void kernel_launch(void* const* d_in, const int* in_sizes, int n_in,
                              void* d_out, int out_size, void* d_ws, size_t ws_size,
                              hipStream_t stream) {
  const float* x   = (const float*)d_in[0];   // [512,384,13,13]
  const float* Wsp = (const float*)d_in[1];   // [512,13,13]
  const float* Wd  = (const float*)d_in[2];   // [512,384]
  const float* Wb  = (const float*)d_in[3];   // [1,512]
  float* out = (float*)d_out;                 // [512,512] fp32

  hipMemsetAsync(d_out, 0, (size_t)out_size * sizeof(float), stream);

  const size_t need = (XF_ELEMS + WSF_ELEMS) * sizeof(__bf16)
                    + WDF_ELEMS * sizeof(float);

  if (ws_size >= need) {
    __bf16* xf  = (__bf16*)d_ws;
    __bf16* wsf = xf + XF_ELEMS;
    float*  wdf = (float*)(wsf + WSF_ELEMS);

    prep_aux_kernel<<<240, 256, 0, stream>>>(Wsp, Wd, wsf, wdf);
    prep_xf_kernel <<<3072, 256, 0, stream>>>(x, xf);

    conv_main_fast<<<6144, 256, 0, stream>>>(xf, wsf, wdf, Wb, out);
  } else {
    dim3 grid(N_ / NT, C_ / CT, B_);
    conv_main_fallback<<<grid, 256, 0, stream>>>(x, Wsp, Wd, Wb, out);
  }
}

// Round 8
// 252.826 us; speedup vs baseline: 1.6317x; 1.1324x over previous
//
#include <hip/hip_runtime.h>

// out[b,n] = sum_{c,hw} x[b,c,hw] * W_s[n,hw] * W_d[n,c] + W_b[n]
// B=512, C=384, N=512, HW=169 (13x13).
//
// R8: SINGLE fused main kernel (prep_xf eliminated).
//  - Block = (b, c_blk): stage the 128x169 fp32 x-slice ONCE into LDS as bf16
//    (vector loads + v_perm truncation + ds_write_b64; no global_load_lds ->
//    the barrier drains only lgkmcnt, no vmcnt(0) DMA stall).
//  - LDS X-tile row stride 200 bf16: rows 16B-aligned (ds_read_b128 legal),
//    window position (m+q) mod 8 uniform -> conflict-free b128.
//  - Loop 4 n-tiles INSIDE the block (X staged once, reused 4x):
//    A-frags from LDS, B-frags direct global->VGPR from wsf (L2-resident,
//    B-fragment order, R5-proven), 96 MFMA per n-tile.
//  - Per n-tile epilogue: fold acc * wdf (C-layout order, R7-proven),
//    shfl 16/32, 1KB LDS cross-wave reduce, atomicAdd; bias on c_blk==0.
//  - x read exactly once grid-wide (133 MB = the HBM floor).

#define B_   512
#define C_   384
#define N_   512
#define HW_  169
#define CT   128
#define SXR  200     // Xs row stride in bf16 (16B-aligned rows, uniform banks)

#define WSF_ELEMS  ((size_t)32 * 6 * 64 * 8)       // 98,304 bf16
#define WDF_ELEMS  ((size_t)24 * 32 * 64 * 4)      // 196,608 f32

typedef __bf16 bf16x8 __attribute__((ext_vector_type(8)));
typedef float f32x4  __attribute__((ext_vector_type(4)));
typedef float f32x4u __attribute__((ext_vector_type(4), aligned(4)));

__device__ __forceinline__ __bf16 f2bf(float f) {
  union { float f; unsigned u; } v; v.f = f;
  unsigned r = (v.u + 0x7FFFu + ((v.u >> 16) & 1u)) >> 16;   // RNE
  unsigned short s = (unsigned short)r;
  return __builtin_bit_cast(__bf16, s);
}

// hi16(a)|hi16(b)<<16 : two bf16 truncations in one v_perm
__device__ __forceinline__ unsigned pack_trunc(float a, float b) {
  return __builtin_amdgcn_perm(__builtin_bit_cast(unsigned, b),
                               __builtin_bit_cast(unsigned, a), 0x07060302u);
}

// ---------------- prep_aux: wsf (B-frag order) + wdf (C-layout order) ----------------
__global__ __launch_bounds__(256)
void prep_aux_kernel(const float* __restrict__ Ws,
                     const float* __restrict__ Wd,
                     __bf16* __restrict__ wsf,
                     float* __restrict__ wdf) {
  int t = blockIdx.x * 256 + threadIdx.x;      // 61440 total, exact
  if (t < 12288) {
    // wsf: t = (nm*6 + kb)*64 + lane ; lane(q=l>>4,m=l&15) holds Ws[nm*16+m][kb*32+q*8+j]
    int lane = t & 63;
    int fr   = t >> 6;
    int kb   = fr % 6;
    int nm   = fr / 6;
    int n    = nm * 16 + (lane & 15);
    int k0   = kb * 32 + (lane >> 4) * 8;
    const float* src = Ws + (size_t)n * HW_;
    bf16x8 v;
    #pragma unroll
    for (int j = 0; j < 8; ++j) {
      int k = k0 + j;
      float f = (k < HW_) ? src[k] : 0.f;
      v[j] = f2bf(f);
    }
    *(bf16x8*)(wsf + (size_t)t * 8) = v;
  } else {
    // wdf: t2 = (cm*32 + nm)*64 + lane; elem i = Wd[nm*16+(l&15)][cm*16+(l>>4)*4+i]
    int t2 = t - 12288;
    int lane = t2 & 63;
    int fr   = t2 >> 6;
    int nm   = fr & 31;
    int cm   = fr >> 5;
    int n    = nm * 16 + (lane & 15);
    int c0   = cm * 16 + (lane >> 4) * 4;
    f32x4 w = *(const f32x4u*)(Wd + (size_t)n * C_ + c0);
    *(f32x4*)(wdf + (size_t)t2 * 4) = w;
  }
}

// ---------------- fused main kernel ----------------
__global__ __launch_bounds__(256, 3)
void conv_fused(const float* __restrict__ x,
                const __bf16* __restrict__ wsf,
                const float* __restrict__ wdf,
                const float* __restrict__ Wb,
                float* __restrict__ out) {
  __shared__ __align__(16) __bf16 Xs[CT * SXR];   // 51.2 KB
  __shared__ float red[4][64];                     // 1 KB

  const int tid  = threadIdx.x;
  // XCD swizzle: the 3 c_blks of one b land on the same id%8 slot.
  const int id    = blockIdx.x;     // 0..1535
  const int slot  = id & 7;
  const int t8    = id >> 3;        // 0..191
  const int c_blk = t8 % 3;
  const int b     = (t8 / 3) * 8 + slot;

  const int lane  = tid & 63;
  const int wv    = tid >> 6;          // 4 waves: 2x2 (c,n) 64x64 quadrants
  const int cq    = (wv >> 1) * 64;
  const int nq    = (wv & 1) * 64;
  const int lrow  = lane & 15;
  const int lquad = lane >> 4;

  // ---- stage X tile: 128 rows x 169 cols fp32 -> bf16 (cols padded to 192) ----
  const float* src = x + ((size_t)b * C_ + (size_t)c_blk * CT) * HW_;
  // 128 rows x 48 chunks(4 cols) = 6144 items = 24/thread exact
  #pragma unroll 4
  for (int p = 0; p < 24; ++p) {
    int i   = p * 256 + tid;
    int row = i / 48;
    int ch  = i - row * 48;
    const float* bp = src + row * HW_ + ch * 4;
    float v0 = 0.f, v1 = 0.f, v2 = 0.f, v3 = 0.f;
    if (ch < 42) {                      // cols ch*4..+3 <= 167
      f32x4u t = *(const f32x4u*)bp;
      v0 = t[0]; v1 = t[1]; v2 = t[2]; v3 = t[3];
    } else if (ch == 42) {              // only col 168 valid
      v0 = bp[0];
    }                                    // ch 43..47: zero pad to col 191
    unsigned d0 = pack_trunc(v0, v1);
    unsigned d1 = pack_trunc(v2, v3);
    uint2 d; d.x = d0; d.y = d1;
    *(uint2*)&Xs[row * SXR + ch * 4] = d;
  }
  __syncthreads();   // lgkm drain only (no DMA queue)

  const int cm0 = c_blk * 8 + (cq >> 4);      // global 16-c fragment row

  // ---- 4 n-tiles, X reused from LDS each time ----
  #pragma unroll 1
  for (int nb = 0; nb < 4; ++nb) {
    const int nm0 = nb * 8 + (nq >> 4);       // global 16-n fragment row
    const __bf16* bbase = wsf + ((size_t)nm0 * 6) * 512 + (size_t)lane * 8;

    const f32x4 zero = {0.f, 0.f, 0.f, 0.f};
    f32x4 acc[4][4];
    #pragma unroll
    for (int mi = 0; mi < 4; ++mi)
      #pragma unroll
      for (int ni = 0; ni < 4; ++ni)
        acc[mi][ni] = zero;

    #pragma unroll
    for (int kb = 0; kb < 6; ++kb) {
      bf16x8 afr[4], bfr[4];
      #pragma unroll
      for (int mi = 0; mi < 4; ++mi)
        afr[mi] = *(const bf16x8*)&Xs[(cq + mi * 16 + lrow) * SXR + kb * 32 + lquad * 8];
      #pragma unroll
      for (int ni = 0; ni < 4; ++ni)
        bfr[ni] = *(const bf16x8*)(bbase + ((size_t)ni * 6 + kb) * 512);
      #pragma unroll
      for (int mi = 0; mi < 4; ++mi)
        #pragma unroll
        for (int ni = 0; ni < 4; ++ni)
          acc[mi][ni] = __builtin_amdgcn_mfma_f32_16x16x32_bf16(
              afr[mi], bfr[ni], acc[mi][ni], 0, 0, 0);
    }

    // fold acc * W_d (wdf in C-layout order; verified R7)
    float s[4] = {0.f, 0.f, 0.f, 0.f};
    #pragma unroll
    for (int ni = 0; ni < 4; ++ni) {
      #pragma unroll
      for (int mi = 0; mi < 4; ++mi) {
        const f32x4 w = *(const f32x4*)(wdf +
            (((size_t)(cm0 + mi) * 32 + (nm0 + ni)) * 64 + lane) * 4);
        s[ni] += acc[mi][ni][0] * w[0] + acc[mi][ni][1] * w[1]
               + acc[mi][ni][2] * w[2] + acc[mi][ni][3] * w[3];
      }
    }

    // intra-wave quad combine (disjoint c, same n)
    #pragma unroll
    for (int ni = 0; ni < 4; ++ni) {
      s[ni] += __shfl_xor(s[ni], 16, 64);
      s[ni] += __shfl_xor(s[ni], 32, 64);
    }
    if (lane < 16) {
      #pragma unroll
      for (int ni = 0; ni < 4; ++ni)
        red[wv][ni * 16 + lrow] = s[ni];
    }
    __syncthreads();

    // waves {0,2} share nq=0, {1,3} share nq=64 (disjoint c halves)
    if (tid < 128) {
      const int half = tid >> 6;
      const int idx  = tid & 63;
      const int n    = nb * 128 + tid;
      float v = red[half][idx] + red[half + 2][idx];
      if (c_blk == 0) v += Wb[n];
      atomicAdd(&out[(size_t)b * N_ + n], v);
    }
    __syncthreads();   // protect red reuse
  }
}

// ---------------- fallback main kernel (no workspace needed) ----------------

#define LDSS 104
#define KCH  96
#define NT   128

__global__ __launch_bounds__(256)
void conv_main_fallback(const float* __restrict__ x,
                        const float* __restrict__ Ws_g,
                        const float* __restrict__ Wd,
                        const float* __restrict__ Wb,
                        float* __restrict__ out) {
  __shared__ __align__(16) __bf16 Xs[CT][LDSS];
  __shared__ __align__(16) __bf16 Ws[NT][LDSS];

  const int tid   = threadIdx.x;
  const int n_blk = blockIdx.x;
  const int c_blk = blockIdx.y;
  const int b     = blockIdx.z;
  const int c0 = c_blk * CT;
  const int n0 = n_blk * NT;
  const int lane  = tid & 63;
  const int wv    = tid >> 6;
  const int cq    = (wv >> 1) * 64;
  const int nq    = (wv & 1) * 64;
  const int lrow  = lane & 15;
  const int lquad = lane >> 4;

  const f32x4 zero = {0.f, 0.f, 0.f, 0.f};
  f32x4 acc[4][4];
  #pragma unroll
  for (int mi = 0; mi < 4; ++mi)
    #pragma unroll
    for (int ni = 0; ni < 4; ++ni)
      acc[mi][ni] = zero;

  const float* xb  = x    + (size_t)b  * (C_ * HW_) + (size_t)c0 * HW_;
  const float* wsb = Ws_g + (size_t)n0 * HW_;

  for (int ch = 0; ch < 2; ++ch) {
    const int k0 = ch * KCH;
    __syncthreads();
    for (int e = tid; e < CT * KCH; e += 256) {
      int r   = e / KCH;
      int col = e - r * KCH;
      int k   = k0 + col;
      float vx = 0.f, vw = 0.f;
      if (k < HW_) {
        vx = xb [r * HW_ + k];
        vw = wsb[r * HW_ + k];
      }
      Xs[r][col] = f2bf(vx);
      Ws[r][col] = f2bf(vw);
    }
    __syncthreads();

    #pragma unroll
    for (int ks = 0; ks < 3; ++ks) {
      const int kc = ks * 32 + lquad * 8;
      bf16x8 afr[4], bfr[4];
      #pragma unroll
      for (int mi = 0; mi < 4; ++mi)
        afr[mi] = *(const bf16x8*)&Xs[cq + mi * 16 + lrow][kc];
      #pragma unroll
      for (int ni = 0; ni < 4; ++ni)
        bfr[ni] = *(const bf16x8*)&Ws[nq + ni * 16 + lrow][kc];
      #pragma unroll
      for (int mi = 0; mi < 4; ++mi)
        #pragma unroll
        for (int ni = 0; ni < 4; ++ni)
          acc[mi][ni] = __builtin_amdgcn_mfma_f32_16x16x32_bf16(
              afr[mi], bfr[ni], acc[mi][ni], 0, 0, 0);
    }
  }

  #pragma unroll
  for (int ni = 0; ni < 4; ++ni) {
    const int n = n0 + nq + ni * 16 + lrow;
    float sv = 0.f;
    #pragma unroll
    for (int mi = 0; mi < 4; ++mi) {
      const int cbase = c0 + cq + mi * 16 + lquad * 4;
      #pragma unroll
      for (int i = 0; i < 4; ++i)
        sv += acc[mi][ni][i] * Wd[(size_t)n * C_ + (cbase + i)];
    }
    sv += __shfl_xor(sv, 16, 64);
    sv += __shfl_xor(sv, 32, 64);
    if (lane < 16) {
      if (c_blk == 0 && cq == 0) sv += Wb[n];
      atomicAdd(&out[(size_t)b * N_ + n], sv);
    }
  }
}

extern "C" void kernel_launch(void* const* d_in, const int* in_sizes, int n_in,
                              void* d_out, int out_size, void* d_ws, size_t ws_size,
                              hipStream_t stream) {
  const float* x   = (const float*)d_in[0];   // [512,384,13,13]
  const float* Wsp = (const float*)d_in[1];   // [512,13,13]
  const float* Wd  = (const float*)d_in[2];   // [512,384]
  const float* Wb  = (const float*)d_in[3];   // [1,512]
  float* out = (float*)d_out;                 // [512,512] fp32

  hipMemsetAsync(d_out, 0, (size_t)out_size * sizeof(float), stream);

  const size_t need = WSF_ELEMS * sizeof(__bf16) + WDF_ELEMS * sizeof(float);

  if (ws_size >= need) {
    __bf16* wsf = (__bf16*)d_ws;
    float*  wdf = (float*)(wsf + WSF_ELEMS);

    prep_aux_kernel<<<240, 256, 0, stream>>>(Wsp, Wd, wsf, wdf);
    conv_fused<<<1536, 256, 0, stream>>>(x, wsf, wdf, Wb, out);
  } else {
    dim3 grid(N_ / NT, C_ / CT, B_);
    conv_main_fallback<<<grid, 256, 0, stream>>>(x, Wsp, Wd, Wb, out);
  }
}